// Round 2
// baseline (996.564 us; speedup 1.0000x reference)
//
#include <hip/hip_runtime.h>

typedef unsigned int u32;
typedef signed char  i8;

#define BM 256
#define BN 256
#define BK 64

typedef __attribute__((ext_vector_type(4))) int   i32x4;
typedef __attribute__((ext_vector_type(4))) float f4v;

// ============================================================
// Fused quantizer, one dispatch (UNCHANGED from round 1 — control):
//   blocks [0, xblocks)      : per-row int8 quantization of x, scale = absmax/127
//   blocks [xblocks, total)  : sign(w) -> int8 in {-1,0,+1}
// ============================================================
__global__ void __launch_bounds__(256) quant_fused(
    const f4v* __restrict__ x, const f4v* __restrict__ w,
    i8* __restrict__ xq, i8* __restrict__ wq, float* __restrict__ s,
    int K, int xblocks)
{
    const int t    = threadIdx.x;
    const int lane = t & 63;
    const int wave = t >> 6;

    if ((int)blockIdx.x < xblocks) {
        const int row = blockIdx.x;
        const f4v* xr = x + (size_t)row * (K >> 2);
        f4v v[4];
        float amax = 0.f;
#pragma unroll
        for (int c = 0; c < 4; ++c) {
            v[c] = __builtin_nontemporal_load(&xr[t + c * 256]);
            amax = fmaxf(amax, fmaxf(fmaxf(fabsf(v[c].x), fabsf(v[c].y)),
                                     fmaxf(fabsf(v[c].z), fabsf(v[c].w))));
        }
#pragma unroll
        for (int off = 32; off > 0; off >>= 1)
            amax = fmaxf(amax, __shfl_down(amax, off));
        __shared__ float red[4];
        if (lane == 0) red[wave] = amax;
        __syncthreads();
        amax = fmaxf(fmaxf(red[0], red[1]), fmaxf(red[2], red[3]));

        const float inv = (amax > 0.f) ? (127.0f / amax) : 0.f;
        if (t == 0) s[row] = amax * (1.0f / 127.0f);

        i8* xo = xq + (size_t)row * K;
#pragma unroll
        for (int c = 0; c < 4; ++c) {
            const int e = (t + c * 256) * 4;
            int q0 = __float2int_rn(v[c].x * inv);
            int q1 = __float2int_rn(v[c].y * inv);
            int q2 = __float2int_rn(v[c].z * inv);
            int q3 = __float2int_rn(v[c].w * inv);
            u32 p = (q0 & 0xFF) | ((q1 & 0xFF) << 8) |
                    ((q2 & 0xFF) << 16) | ((u32)(q3 & 0xFF) << 24);
            *(u32*)&xo[e] = p;
        }
    } else {
        const int b = blockIdx.x - xblocks;
        const f4v* wb = w + (size_t)b * 1024;
        u32* wo = (u32*)(wq + (size_t)b * 4096);
#pragma unroll
        for (int c = 0; c < 4; ++c) {
            const int idx = t + c * 256;
            f4v a = __builtin_nontemporal_load(&wb[idx]);
            u32 b0 = (a.x > 0.f) ? 1u : ((a.x < 0.f) ? 0xFFu : 0u);
            u32 b1 = (a.y > 0.f) ? 1u : ((a.y < 0.f) ? 0xFFu : 0u);
            u32 b2 = (a.z > 0.f) ? 1u : ((a.z < 0.f) ? 0xFFu : 0u);
            u32 b3 = (a.w > 0.f) ? 1u : ((a.w < 0.f) ? 0xFFu : 0u);
            wo[idx] = b0 | (b1 << 8) | (b2 << 16) | (b3 << 24);
        }
    }
}

// async 16B global -> LDS (LDS dest is wave-uniform base + lane*16)
__device__ __forceinline__ void async_cp16(const void* gp, void* lp) {
    __builtin_amdgcn_global_load_lds(
        (__attribute__((address_space(1))) void*)(gp),
        (__attribute__((address_space(3))) void*)(lp),
        16, 0, 0);
}

#define FENCE() asm volatile("" ::: "memory")

// ============================================================
// C[M,N] = (xq . wq^T) * s[row] + bias[col]  -- i8 MFMA, i32 acc
//
// Round 2 change: BK 128 -> 64 so the double-buffered LDS is 64 KB
// -> 2 blocks/CU co-resident (was 1 at 128 KB). Mechanism (m114/m97):
// while one block sits in its stage+vmcnt+barrier drain, the other
// block's waves keep the MFMA pipe fed. Schedule itself (2-phase,
// counted vmcnt(4), never drain-to-0 mid-loop) is unchanged.
//
// Swizzle re-derived for BK=64: LDS row = 64B = 4 x 16B chunks.
// Chunk q of row r stored at q^(r&3); staged by pre-swizzling the
// per-lane GLOBAL address (global_load_lds forces LDS chunk =
// base+lane*16). Reader: fragment (row r, chunk quad) -> LDS byte
// r*64 + ((quad^(r&3))*16). 16 lanes -> 8 distinct bank groups
// (r*16 + q'*4 mod 32) -> 2-way aliasing = free (m136).
// ============================================================
__global__ void __launch_bounds__(512, 4) gemm_i8_bt(
    const i8* __restrict__ A, const i8* __restrict__ B,
    const float* __restrict__ s, const float* __restrict__ bias,
    float* __restrict__ C, int M, int N, int K)
{
    __shared__ i8 lds[2 * 32768];   // [2][ A:16KB | B:16KB ] = 64 KB

    const int t    = threadIdx.x;
    const int lane = t & 63;
    const int wave = t >> 6;
    const int wm   = (wave >> 2) * 128;   // 2 waves in M, 128 rows each
    const int wn   = (wave & 3) * 64;     // 4 waves in N, 64 cols each
    const int l15  = lane & 15;
    const int quad = lane >> 4;
    const int sw   = l15 & 3;             // reader swizzle key (row&3)

    // XCD-aware decode: 512 blocks, xcd = bid&7, 8x8 patch per XCD (bijective)
    const int nbm = M / BM, nbn = N / BN;
    int mb, nb;
    const int bid = blockIdx.x;
    if (nbm == 32 && nbn == 16) {
        const int xcd   = bid & 7;
        const int local = bid >> 3;            // 64 blocks per XCD
        mb = ((xcd >> 1) << 3) + (local >> 3);
        nb = ((xcd & 1) << 3) + (local & 7);
    } else {
        mb = bid / nbn;
        nb = bid - mb * nbn;
    }
    const size_t m_block = (size_t)mb * BM;
    const size_t n_block = (size_t)nb * BN;

    i32x4 acc[8][4];
#pragma unroll
    for (int i = 0; i < 8; ++i)
#pragma unroll
        for (int j = 0; j < 4; ++j)
            acc[i][j] = (i32x4){0, 0, 0, 0};

    // staging map: each half (A or B) = 256 rows x 64B = 1024 x 16B chunks;
    // thread covers chunks c = t + s*512 (s=0,1). LDS chunk c <- global
    // (row = c>>2, chunk (c&3)^(row&3)). 32-bit offsets keep VGPR low.
    const i8* Abase = A + m_block * K;
    const i8* Bbase = B + n_block * K;
    u32 offG[2], lofs[2];
#pragma unroll
    for (int sidx = 0; sidx < 2; ++sidx) {
        const int c  = t + sidx * 512;
        const int r  = c >> 2;
        const int gq = (c & 3) ^ (r & 3);
        lofs[sidx] = (u32)c * 16u;
        offG[sidx] = (u32)(r * K + gq * 16);
    }

    const int NT = K / BK;   // 64

#define STAGE(buf, kofs)                                                    \
    do {                                                                    \
        i8* lbA = lds + (buf) * 32768;                                      \
        i8* lbB = lbA + 16384;                                              \
        _Pragma("unroll")                                                   \
        for (int s_ = 0; s_ < 2; ++s_)                                      \
            async_cp16(Abase + offG[s_] + (kofs), lbA + lofs[s_]);          \
        _Pragma("unroll")                                                   \
        for (int s_ = 0; s_ < 2; ++s_)                                      \
            async_cp16(Bbase + offG[s_] + (kofs), lbB + lofs[s_]);          \
    } while (0)

    // prologue: fill both buffers; wait only for buffer 0 (oldest 4 loads)
    STAGE(0, 0);
    STAGE(1, BK);
    asm volatile("s_waitcnt vmcnt(4)" ::: "memory");
    __builtin_amdgcn_s_barrier();
    FENCE();

    for (int tile = 0; tile < NT; ++tile) {
        const int cur = tile & 1;
        const i8* Abuf = lds + cur * 32768;
        const i8* Bbuf = Abuf + 16384;

        {
            const int cq = (quad ^ sw) * 16;
            i32x4 af[8], bf[4];
#pragma unroll
            for (int nj = 0; nj < 4; ++nj)
                bf[nj] = *(const i32x4*)&Bbuf[(u32)(wn + nj * 16 + l15) * BK + cq];
#pragma unroll
            for (int mi = 0; mi < 8; ++mi)
                af[mi] = *(const i32x4*)&Abuf[(u32)(wm + mi * 16 + l15) * BK + cq];
#pragma unroll
            for (int mi = 0; mi < 8; ++mi)
#pragma unroll
                for (int nj = 0; nj < 4; ++nj)
                    acc[mi][nj] = __builtin_amdgcn_mfma_i32_16x16x64_i8(
                        af[mi], bf[nj], acc[mi][nj], 0, 0, 0);
        }

        FENCE();
        __builtin_amdgcn_s_barrier();      // all waves done READING buf[cur]
        FENCE();
        if (tile + 2 < NT) {
            STAGE(cur, (tile + 2) * BK);   // overwrite just-consumed buffer
            asm volatile("s_waitcnt vmcnt(4)" ::: "memory");  // tile+1 landed
        } else {
            asm volatile("s_waitcnt vmcnt(0)" ::: "memory");  // drain at end
        }
        __builtin_amdgcn_s_barrier();      // buf[cur^1] fully staged
        FENCE();
    }
#undef STAGE

    // epilogue: C/D layout col=lane&15, row=quad*4+reg (dtype-independent)
    float bv[4];
#pragma unroll
    for (int nj = 0; nj < 4; ++nj)
        bv[nj] = bias[n_block + wn + nj * 16 + l15];

#pragma unroll
    for (int mi = 0; mi < 8; ++mi) {
        const size_t row0 = m_block + wm + mi * 16 + quad * 4;
        const f4v sv = *(const f4v*)&s[row0];
#pragma unroll
        for (int nj = 0; nj < 4; ++nj) {
            const size_t col = n_block + wn + nj * 16 + l15;
            __builtin_nontemporal_store((float)acc[mi][nj][0] * sv.x + bv[nj], &C[(row0 + 0) * N + col]);
            __builtin_nontemporal_store((float)acc[mi][nj][1] * sv.y + bv[nj], &C[(row0 + 1) * N + col]);
            __builtin_nontemporal_store((float)acc[mi][nj][2] * sv.z + bv[nj], &C[(row0 + 2) * N + col]);
            __builtin_nontemporal_store((float)acc[mi][nj][3] * sv.w + bv[nj], &C[(row0 + 3) * N + col]);
        }
    }
}

extern "C" void kernel_launch(void* const* d_in, const int* in_sizes, int n_in,
                              void* d_out, int out_size, void* d_ws, size_t ws_size,
                              hipStream_t stream) {
    const float* x  = (const float*)d_in[0];   // [M,K]
    const float* w  = (const float*)d_in[1];   // [N,K]
    const float* bs = (const float*)d_in[2];   // [N]
    float* out = (float*)d_out;                // [M,N]

    const int N = in_sizes[2];
    const int K = in_sizes[1] / N;
    const int M = in_sizes[0] / K;

    i8*    xq = (i8*)d_ws;                          // [M,K] int8
    i8*    wq = xq + (size_t)M * K;                 // [N,K] int8 (+-1)
    float* s  = (float*)(wq + (size_t)N * K);       // [M] fp32 row scales

    const int xblocks = M;
    const int wblocks = (int)(((size_t)N * K) / (256 * 16));
    quant_fused<<<xblocks + wblocks, 256, 0, stream>>>(
        (const f4v*)x, (const f4v*)w, xq, wq, s, K, xblocks);

    const int nblocks = (M / BM) * (N / BN);   // 512
    gemm_i8_bt<<<nblocks, 512, 0, stream>>>(xq, wq, s, bs, out, M, N, K);
}

// Round 3
// 385.374 us; speedup vs baseline: 2.5860x; 2.5860x over previous
//
#include <hip/hip_runtime.h>

typedef unsigned int u32;
typedef signed char  i8;

#define BM 256
#define BN 256
#define BK 64
#define NBUF 3
#define BUFSZ 32768   /* A 16KB + B 16KB per K-tile */

typedef __attribute__((ext_vector_type(4))) int   i32x4;
typedef __attribute__((ext_vector_type(4))) float f4v;

// ============================================================
// Fused quantizer, one dispatch (UNCHANGED — control):
//   blocks [0, xblocks)      : per-row int8 quantization of x, scale = absmax/127
//   blocks [xblocks, total)  : sign(w) -> int8 in {-1,0,+1}
// ============================================================
__global__ void __launch_bounds__(256) quant_fused(
    const f4v* __restrict__ x, const f4v* __restrict__ w,
    i8* __restrict__ xq, i8* __restrict__ wq, float* __restrict__ s,
    int K, int xblocks)
{
    const int t    = threadIdx.x;
    const int lane = t & 63;
    const int wave = t >> 6;

    if ((int)blockIdx.x < xblocks) {
        const int row = blockIdx.x;
        const f4v* xr = x + (size_t)row * (K >> 2);
        f4v v[4];
        float amax = 0.f;
#pragma unroll
        for (int c = 0; c < 4; ++c) {
            v[c] = __builtin_nontemporal_load(&xr[t + c * 256]);
            amax = fmaxf(amax, fmaxf(fmaxf(fabsf(v[c].x), fabsf(v[c].y)),
                                     fmaxf(fabsf(v[c].z), fabsf(v[c].w))));
        }
#pragma unroll
        for (int off = 32; off > 0; off >>= 1)
            amax = fmaxf(amax, __shfl_down(amax, off));
        __shared__ float red[4];
        if (lane == 0) red[wave] = amax;
        __syncthreads();
        amax = fmaxf(fmaxf(red[0], red[1]), fmaxf(red[2], red[3]));

        const float inv = (amax > 0.f) ? (127.0f / amax) : 0.f;
        if (t == 0) s[row] = amax * (1.0f / 127.0f);

        i8* xo = xq + (size_t)row * K;
#pragma unroll
        for (int c = 0; c < 4; ++c) {
            const int e = (t + c * 256) * 4;
            int q0 = __float2int_rn(v[c].x * inv);
            int q1 = __float2int_rn(v[c].y * inv);
            int q2 = __float2int_rn(v[c].z * inv);
            int q3 = __float2int_rn(v[c].w * inv);
            u32 p = (q0 & 0xFF) | ((q1 & 0xFF) << 8) |
                    ((q2 & 0xFF) << 16) | ((u32)(q3 & 0xFF) << 24);
            *(u32*)&xo[e] = p;
        }
    } else {
        const int b = blockIdx.x - xblocks;
        const f4v* wb = w + (size_t)b * 1024;
        u32* wo = (u32*)(wq + (size_t)b * 4096);
#pragma unroll
        for (int c = 0; c < 4; ++c) {
            const int idx = t + c * 256;
            f4v a = __builtin_nontemporal_load(&wb[idx]);
            u32 b0 = (a.x > 0.f) ? 1u : ((a.x < 0.f) ? 0xFFu : 0u);
            u32 b1 = (a.y > 0.f) ? 1u : ((a.y < 0.f) ? 0xFFu : 0u);
            u32 b2 = (a.z > 0.f) ? 1u : ((a.z < 0.f) ? 0xFFu : 0u);
            u32 b3 = (a.w > 0.f) ? 1u : ((a.w < 0.f) ? 0xFFu : 0u);
            wo[idx] = b0 | (b1 << 8) | (b2 << 16) | (b3 << 24);
        }
    }
}

// async 16B global -> LDS (LDS dest is wave-uniform base + lane*16)
__device__ __forceinline__ void async_cp16(const void* gp, void* lp) {
    __builtin_amdgcn_global_load_lds(
        (__attribute__((address_space(1))) void*)(gp),
        (__attribute__((address_space(3))) void*)(lp),
        16, 0, 0);
}

#define FENCE() asm volatile("" ::: "memory")

// ============================================================
// C[M,N] = (xq . wq^T) * s[row] + bias[col]  -- i8 MFMA, i32 acc
//
// Round 3: m201-style phase schedule at the known-good register budget.
//  - 256x256 tile, 8 waves (2Mx4N), __launch_bounds__(512,2): <=256 regs,
//    acc(128)+af/bf(32)+addr ~ 180 -> NO spill (round-2 lesson: (512,4)
//    capped regs at 128 < acc alone -> 2.6GB scratch traffic).
//  - BK=64 -> 32KB per K-tile; THREE buffers (96KB LDS) rotate so tile t+2
//    is staged during tile t (2-K-tile lead ~2600cy >> 900cy HBM latency),
//    2 global_load_lds per phase (spread), counted vmcnt(4) ONCE per
//    K-tile, never 0 in the main loop (T3+T4).
//  - 2 phases per K-tile: P0 = {bf[0..3],af[0..3] ds_read; stage A-half;
//    barrier; lgkmcnt(0); setprio(1); 16 MFMA; setprio(0); barrier},
//    P1 = {af[4..7]; stage B-half; ...; vmcnt; barrier}. (T5 setprio has
//    phase role-split to arbitrate.)
//  - Paired-row swizzle for 64B rows (round-2's 4-chunk XOR was a 4-way
//    conflict): two rows share a 128B line; global chunk (r,q) lives at
//    line r>>1, slot (((r&1)<<2)|q) ^ ((r>>1)&7). A wave's ds_read_b128
//    (rows wX+f*16+l15, chunk quad) covers 8 full 128B lines bijectively
//    -> conflict-free. Staging inverts the map on the global address
//    (global_load_lds dest is forced linear).
// ============================================================
__global__ void __launch_bounds__(512, 2) gemm_i8_bt(
    const i8* __restrict__ A, const i8* __restrict__ B,
    const float* __restrict__ s, const float* __restrict__ bias,
    float* __restrict__ C, int M, int N, int K)
{
    extern __shared__ i8 lds[];   // NBUF * BUFSZ = 96 KB

    const int t    = threadIdx.x;
    const int lane = t & 63;
    const int wave = t >> 6;
    const int wm   = (wave >> 2) * 128;   // 2 waves in M, 128 rows each
    const int wn   = (wave & 3) * 64;     // 4 waves in N, 64 cols each
    const int l15  = lane & 15;
    const int quad = lane >> 4;

    // XCD-aware decode: 512 blocks, xcd = bid&7, 8x8 patch per XCD (bijective)
    const int nbm = M / BM, nbn = N / BN;
    int mb, nb;
    const int bid = blockIdx.x;
    if (nbm == 32 && nbn == 16) {
        const int xcd   = bid & 7;
        const int local = bid >> 3;            // 64 blocks per XCD
        mb = ((xcd >> 1) << 3) + (local >> 3);
        nb = ((xcd & 1) << 3) + (local & 7);
    } else {
        mb = bid / nbn;
        nb = bid - mb * nbn;
    }
    const size_t m_block = (size_t)mb * BM;
    const size_t n_block = (size_t)nb * BN;

    i32x4 acc[8][4];
#pragma unroll
    for (int i = 0; i < 8; ++i)
#pragma unroll
        for (int j = 0; j < 4; ++j)
            acc[i][j] = (i32x4){0, 0, 0, 0};

    // reader LDS byte bases: fragment (row r, chunk quad),
    // byte = (r>>1)*128 + ((((r&1)<<2)|quad) ^ ((r>>1)&7))*16.
    // r = wX + f*16 + l15 => (r&1)=l15&1, key=((l15>>1)&7) const across f;
    // per-fragment step is +1024 bytes (f*16 rows = f*8 lines).
    const int slot = ((((l15 & 1) << 2) | quad) ^ ((l15 >> 1) & 7));
    const u32 aoff = (u32)(wm * 64 + (l15 >> 1) * 128 + slot * 16);
    const u32 boff = (u32)(16384 + wn * 64 + (l15 >> 1) * 128 + slot * 16);

    // staging map (inverse swizzle on the global side):
    // LDS chunk c: line=c>>3, sl=c&7, l=sl^(line&7), r=line*2+(l>>2), q=l&3
    const i8* Abase = A + m_block * K;
    const i8* Bbase = B + n_block * K;
    u32 goff[2], lofs[2];
#pragma unroll
    for (int sidx = 0; sidx < 2; ++sidx) {
        const int c    = t + sidx * 512;
        const int line = c >> 3;
        const int sl   = c & 7;
        const int l    = sl ^ (line & 7);
        const int r    = line * 2 + (l >> 2);
        const int q    = l & 3;
        goff[sidx] = (u32)(r * K + q * 16);
        lofs[sidx] = (u32)c * 16u;
    }

    const int NT = K / BK;   // 64

#define STAGE_A(buf, kofs)                                                   \
    do {                                                                     \
        i8* lb = lds + (buf) * BUFSZ;                                        \
        async_cp16(Abase + goff[0] + (kofs), lb + lofs[0]);                  \
        async_cp16(Abase + goff[1] + (kofs), lb + lofs[1]);                  \
    } while (0)
#define STAGE_B(buf, kofs)                                                   \
    do {                                                                     \
        i8* lb = lds + (buf) * BUFSZ + 16384;                                \
        async_cp16(Bbase + goff[0] + (kofs), lb + lofs[0]);                  \
        async_cp16(Bbase + goff[1] + (kofs), lb + lofs[1]);                  \
    } while (0)

    // prologue: stage tiles 0,1; wait tile 0 (4 oldest of 8), keep 4 flying
    STAGE_A(0, 0); STAGE_B(0, 0);
    STAGE_A(1, BK); STAGE_B(1, BK);
    asm volatile("s_waitcnt vmcnt(4)" ::: "memory");
    __builtin_amdgcn_s_barrier();
    FENCE();

    int cur = 0, nx2 = 2;
    for (int tile = 0; tile < NT; ++tile) {
        const i8* buf = lds + cur * BUFSZ;
        const bool st = (tile + 2 < NT);
        const int kofs2 = (tile + 2) * BK;

        i32x4 af[4], bf[4];

        // ---- phase 0: C rows wm..wm+63 ----
#pragma unroll
        for (int nj = 0; nj < 4; ++nj)
            bf[nj] = *(const i32x4*)&buf[boff + nj * 1024];
#pragma unroll
        for (int mi = 0; mi < 4; ++mi)
            af[mi] = *(const i32x4*)&buf[aoff + mi * 1024];
        if (st) STAGE_A(nx2, kofs2);
        __builtin_amdgcn_sched_barrier(0);
        FENCE();
        __builtin_amdgcn_s_barrier();
        asm volatile("s_waitcnt lgkmcnt(0)" ::: "memory");
        __builtin_amdgcn_sched_barrier(0);
        __builtin_amdgcn_s_setprio(1);
#pragma unroll
        for (int mi = 0; mi < 4; ++mi)
#pragma unroll
            for (int nj = 0; nj < 4; ++nj)
                acc[mi][nj] = __builtin_amdgcn_mfma_i32_16x16x64_i8(
                    af[mi], bf[nj], acc[mi][nj], 0, 0, 0);
        __builtin_amdgcn_s_setprio(0);
        FENCE();
        __builtin_amdgcn_s_barrier();
        FENCE();

        // ---- phase 1: C rows wm+64..wm+127 (bf reused in regs) ----
#pragma unroll
        for (int mi = 0; mi < 4; ++mi)
            af[mi] = *(const i32x4*)&buf[aoff + (mi + 4) * 1024];
        if (st) STAGE_B(nx2, kofs2);
        __builtin_amdgcn_sched_barrier(0);
        FENCE();
        __builtin_amdgcn_s_barrier();
        asm volatile("s_waitcnt lgkmcnt(0)" ::: "memory");
        __builtin_amdgcn_sched_barrier(0);
        __builtin_amdgcn_s_setprio(1);
#pragma unroll
        for (int mi = 0; mi < 4; ++mi)
#pragma unroll
            for (int nj = 0; nj < 4; ++nj)
                acc[mi + 4][nj] = __builtin_amdgcn_mfma_i32_16x16x64_i8(
                    af[mi], bf[nj], acc[mi + 4][nj], 0, 0, 0);
        __builtin_amdgcn_s_setprio(0);

        // K-tile boundary: wait tile+1 landed (tile+2's 4 stay in flight)
        if (st) { asm volatile("s_waitcnt vmcnt(4)" ::: "memory"); }
        else    { asm volatile("s_waitcnt vmcnt(0)" ::: "memory"); }
        FENCE();
        __builtin_amdgcn_s_barrier();
        FENCE();

        cur = (cur == NBUF - 1) ? 0 : cur + 1;
        nx2 = (nx2 == NBUF - 1) ? 0 : nx2 + 1;
    }
#undef STAGE_A
#undef STAGE_B

    // epilogue: C/D layout col=lane&15, row=quad*4+reg (dtype-independent)
    float bv[4];
#pragma unroll
    for (int nj = 0; nj < 4; ++nj)
        bv[nj] = bias[n_block + wn + nj * 16 + l15];

#pragma unroll
    for (int mi = 0; mi < 8; ++mi) {
        const size_t row0 = m_block + wm + mi * 16 + quad * 4;
        const f4v sv = *(const f4v*)&s[row0];
#pragma unroll
        for (int nj = 0; nj < 4; ++nj) {
            const size_t col = n_block + wn + nj * 16 + l15;
            __builtin_nontemporal_store((float)acc[mi][nj][0] * sv.x + bv[nj], &C[(row0 + 0) * N + col]);
            __builtin_nontemporal_store((float)acc[mi][nj][1] * sv.y + bv[nj], &C[(row0 + 1) * N + col]);
            __builtin_nontemporal_store((float)acc[mi][nj][2] * sv.z + bv[nj], &C[(row0 + 2) * N + col]);
            __builtin_nontemporal_store((float)acc[mi][nj][3] * sv.w + bv[nj], &C[(row0 + 3) * N + col]);
        }
    }
}

extern "C" void kernel_launch(void* const* d_in, const int* in_sizes, int n_in,
                              void* d_out, int out_size, void* d_ws, size_t ws_size,
                              hipStream_t stream) {
    const float* x  = (const float*)d_in[0];   // [M,K]
    const float* w  = (const float*)d_in[1];   // [N,K]
    const float* bs = (const float*)d_in[2];   // [N]
    float* out = (float*)d_out;                // [M,N]

    const int N = in_sizes[2];
    const int K = in_sizes[1] / N;
    const int M = in_sizes[0] / K;

    i8*    xq = (i8*)d_ws;                          // [M,K] int8
    i8*    wq = xq + (size_t)M * K;                 // [N,K] int8 (+-1)
    float* s  = (float*)(wq + (size_t)N * K);       // [M] fp32 row scales

    const int xblocks = M;
    const int wblocks = (int)(((size_t)N * K) / (256 * 16));
    quant_fused<<<xblocks + wblocks, 256, 0, stream>>>(
        (const f4v*)x, (const f4v*)w, xq, wq, s, K, xblocks);

    // 96 KB dynamic LDS needs the opt-in (static limit is 64 KB).
    static bool lds_opt_in = false;
    if (!lds_opt_in) {
        hipFuncSetAttribute((const void*)gemm_i8_bt,
                            hipFuncAttributeMaxDynamicSharedMemorySize,
                            NBUF * BUFSZ);
        lds_opt_in = true;
    }
    const int nblocks = (M / BM) * (N / BN);   // 512
    gemm_i8_bt<<<nblocks, 512, NBUF * BUFSZ, stream>>>(xq, wq, s, bs, out, M, N, K);
}

// Round 4
// 372.242 us; speedup vs baseline: 2.6772x; 1.0353x over previous
//
#include <hip/hip_runtime.h>

typedef unsigned int u32;
typedef signed char  i8;

#define BM 256
#define BN 256
#define BK 64
#define NBUF 3
#define BUFSZ 32768   /* A 16KB + B 16KB per K-tile */

typedef __attribute__((ext_vector_type(4))) int   i32x4;
typedef __attribute__((ext_vector_type(4))) float f4v;

// ============================================================
// Fused quantizer, one dispatch (UNCHANGED — control):
//   blocks [0, xblocks)      : per-row int8 quantization of x, scale = absmax/127
//   blocks [xblocks, total)  : sign(w) -> int8 in {-1,0,+1}
// ============================================================
__global__ void __launch_bounds__(256) quant_fused(
    const f4v* __restrict__ x, const f4v* __restrict__ w,
    i8* __restrict__ xq, i8* __restrict__ wq, float* __restrict__ s,
    int K, int xblocks)
{
    const int t    = threadIdx.x;
    const int lane = t & 63;
    const int wave = t >> 6;

    if ((int)blockIdx.x < xblocks) {
        const int row = blockIdx.x;
        const f4v* xr = x + (size_t)row * (K >> 2);
        f4v v[4];
        float amax = 0.f;
#pragma unroll
        for (int c = 0; c < 4; ++c) {
            v[c] = __builtin_nontemporal_load(&xr[t + c * 256]);
            amax = fmaxf(amax, fmaxf(fmaxf(fabsf(v[c].x), fabsf(v[c].y)),
                                     fmaxf(fabsf(v[c].z), fabsf(v[c].w))));
        }
#pragma unroll
        for (int off = 32; off > 0; off >>= 1)
            amax = fmaxf(amax, __shfl_down(amax, off));
        __shared__ float red[4];
        if (lane == 0) red[wave] = amax;
        __syncthreads();
        amax = fmaxf(fmaxf(red[0], red[1]), fmaxf(red[2], red[3]));

        const float inv = (amax > 0.f) ? (127.0f / amax) : 0.f;
        if (t == 0) s[row] = amax * (1.0f / 127.0f);

        i8* xo = xq + (size_t)row * K;
#pragma unroll
        for (int c = 0; c < 4; ++c) {
            const int e = (t + c * 256) * 4;
            int q0 = __float2int_rn(v[c].x * inv);
            int q1 = __float2int_rn(v[c].y * inv);
            int q2 = __float2int_rn(v[c].z * inv);
            int q3 = __float2int_rn(v[c].w * inv);
            u32 p = (q0 & 0xFF) | ((q1 & 0xFF) << 8) |
                    ((q2 & 0xFF) << 16) | ((u32)(q3 & 0xFF) << 24);
            *(u32*)&xo[e] = p;
        }
    } else {
        const int b = blockIdx.x - xblocks;
        const f4v* wb = w + (size_t)b * 1024;
        u32* wo = (u32*)(wq + (size_t)b * 4096);
#pragma unroll
        for (int c = 0; c < 4; ++c) {
            const int idx = t + c * 256;
            f4v a = __builtin_nontemporal_load(&wb[idx]);
            u32 b0 = (a.x > 0.f) ? 1u : ((a.x < 0.f) ? 0xFFu : 0u);
            u32 b1 = (a.y > 0.f) ? 1u : ((a.y < 0.f) ? 0xFFu : 0u);
            u32 b2 = (a.z > 0.f) ? 1u : ((a.z < 0.f) ? 0xFFu : 0u);
            u32 b3 = (a.w > 0.f) ? 1u : ((a.w < 0.f) ? 0xFFu : 0u);
            wo[idx] = b0 | (b1 << 8) | (b2 << 16) | (b3 << 24);
        }
    }
}

// async 16B global -> LDS (LDS dest is wave-uniform base + lane*16)
__device__ __forceinline__ void async_cp16(const void* gp, void* lp) {
    __builtin_amdgcn_global_load_lds(
        (__attribute__((address_space(1))) void*)(gp),
        (__attribute__((address_space(3))) void*)(lp),
        16, 0, 0);
}

#define FENCE() asm volatile("" ::: "memory")

// ============================================================
// C[M,N] = (xq . wq^T) * s[row] + bias[col]  -- i8 MFMA, i32 acc
//
// Round 4: software-pipelined fragment reads (the piece rounds 1/3 missed).
// Measured model: per K-tile LDS-read burst ~1150 cyc and MFMA ~1307 cyc ran
// back-to-back (3150 cyc measured = serial sum) because lgkmcnt(0) preceded
// every MFMA cluster. Now every ds_read burst is issued one MFMA-cluster
// early and NO explicit lgkm drain exists; the compiler inserts minimal
// lgkmcnt(N) before first use (proven m97 asm), so LDS service overlaps MFMA:
//   P0(t): read af4..7(t) | barrier | stage A(t+2) | MFMA af0..3(t) x bf(t)
//   P1(t): vmcnt(2) | barrier | read bf,af0..3(t+1) | stage B(t+2)
//          | MFMA af4..7(t) x bf(t)
// Counted vmcnt(2): tile t+1 fully staged, tile t+2's A-half stays in flight;
// never drains to 0 mid-loop (T4). Register ping-pong set0/set1, unroll x2
// (all indices static, rule #20). 2 barriers/tile (was 4). 3-buffer LDS.
// Safety: barrier-instance counting + compiler lgkm-before-use ==> every
// wave's reads of slot (t+2)%3 completed before any wave restages it.
// Swizzle identical to round 3 (measured 0 conflicts).
// ============================================================
__global__ void __launch_bounds__(512, 2) gemm_i8_bt(
    const i8* __restrict__ A, const i8* __restrict__ B,
    const float* __restrict__ s, const float* __restrict__ bias,
    float* __restrict__ C, int M, int N, int K)
{
    extern __shared__ i8 lds[];   // NBUF * BUFSZ = 96 KB

    const int t    = threadIdx.x;
    const int lane = t & 63;
    const int wave = t >> 6;
    const int wm   = (wave >> 2) * 128;   // 2 waves in M, 128 rows each
    const int wn   = (wave & 3) * 64;     // 4 waves in N, 64 cols each
    const int l15  = lane & 15;
    const int quad = lane >> 4;

    // XCD-aware decode: 512 blocks, xcd = bid&7, 8x8 patch per XCD (bijective)
    const int nbm = M / BM, nbn = N / BN;
    int mb, nb;
    const int bid = blockIdx.x;
    if (nbm == 32 && nbn == 16) {
        const int xcd   = bid & 7;
        const int local = bid >> 3;            // 64 blocks per XCD
        mb = ((xcd >> 1) << 3) + (local >> 3);
        nb = ((xcd & 1) << 3) + (local & 7);
    } else {
        mb = bid / nbn;
        nb = bid - mb * nbn;
    }
    const size_t m_block = (size_t)mb * BM;
    const size_t n_block = (size_t)nb * BN;

    i32x4 acc[8][4];
#pragma unroll
    for (int i = 0; i < 8; ++i)
#pragma unroll
        for (int j = 0; j < 4; ++j)
            acc[i][j] = (i32x4){0, 0, 0, 0};

    // reader LDS byte bases (paired-row swizzle, 0-conflict measured r3):
    // fragment (row r, chunk quad): byte=(r>>1)*128+((((r&1)<<2)|quad)^((r>>1)&7))*16
    const int slot = ((((l15 & 1) << 2) | quad) ^ ((l15 >> 1) & 7));
    const u32 aoff = (u32)(wm * 64 + (l15 >> 1) * 128 + slot * 16);
    const u32 boff = (u32)(16384 + wn * 64 + (l15 >> 1) * 128 + slot * 16);

    // staging map (inverse swizzle on the global side):
    // LDS chunk c: line=c>>3, sl=c&7, l=sl^(line&7), r=line*2+(l>>2), q=l&3
    const i8* Abase = A + m_block * K;
    const i8* Bbase = B + n_block * K;
    u32 goff[2], lofs[2];
#pragma unroll
    for (int sidx = 0; sidx < 2; ++sidx) {
        const int c    = t + sidx * 512;
        const int line = c >> 3;
        const int sl   = c & 7;
        const int l    = sl ^ (line & 7);
        const int r    = line * 2 + (l >> 2);
        const int q    = l & 3;
        goff[sidx] = (u32)(r * K + q * 16);
        lofs[sidx] = (u32)c * 16u;
    }

    const int NT = K / BK;   // 64

#define STAGE_A(buf, kofs)                                                   \
    do {                                                                     \
        i8* lb = lds + (buf) * BUFSZ;                                        \
        async_cp16(Abase + goff[0] + (kofs), lb + lofs[0]);                  \
        async_cp16(Abase + goff[1] + (kofs), lb + lofs[1]);                  \
    } while (0)
#define STAGE_B(buf, kofs)                                                   \
    do {                                                                     \
        i8* lb = lds + (buf) * BUFSZ + 16384;                                \
        async_cp16(Bbase + goff[0] + (kofs), lb + lofs[0]);                  \
        async_cp16(Bbase + goff[1] + (kofs), lb + lofs[1]);                  \
    } while (0)

    i32x4 a47[4];
    i32x4 af0[4], bf0[4];   // fragment set 0 (tiles 0,2,4,..)
    i32x4 af1[4], bf1[4];   // fragment set 1 (tiles 1,3,5,..)

// P0(t): issue af4..7(t), barrier, stage A(t+2), MFMA af0..3(t) x bf(t)
#define PHASE0(T, AFc, BFc, DO_STAGE)                                        \
    do {                                                                     \
        const i8* bufc_ = lds + ((T) % 3) * BUFSZ;                           \
        _Pragma("unroll")                                                    \
        for (int mi = 0; mi < 4; ++mi)                                       \
            a47[mi] = *(const i32x4*)&bufc_[aoff + (mi + 4) * 1024];         \
        __builtin_amdgcn_sched_barrier(0);                                   \
        if (DO_STAGE) {                                                      \
            FENCE(); __builtin_amdgcn_s_barrier(); FENCE();                  \
            STAGE_A(((T) + 2) % 3, ((T) + 2) * BK);                          \
        }                                                                    \
        __builtin_amdgcn_sched_barrier(0);                                   \
        __builtin_amdgcn_s_setprio(1);                                       \
        _Pragma("unroll")                                                    \
        for (int mi = 0; mi < 4; ++mi)                                       \
            _Pragma("unroll")                                                \
            for (int nj = 0; nj < 4; ++nj)                                   \
                acc[mi][nj] = __builtin_amdgcn_mfma_i32_16x16x64_i8(         \
                    AFc[mi], BFc[nj], acc[mi][nj], 0, 0, 0);                 \
        __builtin_amdgcn_s_setprio(0);                                       \
        __builtin_amdgcn_sched_barrier(0);                                   \
    } while (0)

// P1(t): vmcnt, barrier, issue bf/af0..3(t+1), stage B(t+2),
//        MFMA af4..7(t) x bf(t)
#define PHASE1(T, BFc, AFn, BFn, VM2, DO_RD, DO_STAGE)                       \
    do {                                                                     \
        if (VM2) asm volatile("s_waitcnt vmcnt(2)" ::: "memory");            \
        else     asm volatile("s_waitcnt vmcnt(0)" ::: "memory");            \
        FENCE(); __builtin_amdgcn_s_barrier(); FENCE();                      \
        if (DO_RD) {                                                         \
            const i8* bufn_ = lds + (((T) + 1) % 3) * BUFSZ;                 \
            _Pragma("unroll")                                                \
            for (int nj = 0; nj < 4; ++nj)                                   \
                BFn[nj] = *(const i32x4*)&bufn_[boff + nj * 1024];           \
            _Pragma("unroll")                                                \
            for (int mi = 0; mi < 4; ++mi)                                   \
                AFn[mi] = *(const i32x4*)&bufn_[aoff + mi * 1024];           \
        }                                                                    \
        if (DO_STAGE) STAGE_B(((T) + 2) % 3, ((T) + 2) * BK);                \
        __builtin_amdgcn_sched_barrier(0);                                   \
        __builtin_amdgcn_s_setprio(1);                                       \
        _Pragma("unroll")                                                    \
        for (int mi = 0; mi < 4; ++mi)                                       \
            _Pragma("unroll")                                                \
            for (int nj = 0; nj < 4; ++nj)                                   \
                acc[mi + 4][nj] = __builtin_amdgcn_mfma_i32_16x16x64_i8(     \
                    a47[mi], BFc[nj], acc[mi + 4][nj], 0, 0, 0);             \
        __builtin_amdgcn_s_setprio(0);                                       \
        __builtin_amdgcn_sched_barrier(0);                                   \
    } while (0)

    // prologue: stage tiles 0,1 (8 loads); wait tile 0 only (4 stay flying);
    // preload tile-0 fragments into set 0.
    STAGE_A(0, 0); STAGE_B(0, 0);
    STAGE_A(1, BK); STAGE_B(1, BK);
    asm volatile("s_waitcnt vmcnt(4)" ::: "memory");
    FENCE(); __builtin_amdgcn_s_barrier(); FENCE();
    {
        const i8* buf0_ = lds;
#pragma unroll
        for (int nj = 0; nj < 4; ++nj)
            bf0[nj] = *(const i32x4*)&buf0_[boff + nj * 1024];
#pragma unroll
        for (int mi = 0; mi < 4; ++mi)
            af0[mi] = *(const i32x4*)&buf0_[aoff + mi * 1024];
    }

    // main loop: t = 0 .. NT-3 always stages (t+2 <= NT-1); even iteration
    // count (NT-2 = 62) -> clean x2 unroll with static register ping-pong.
    for (int tt = 0; tt < NT - 2; tt += 2) {
        PHASE0(tt, af0, bf0, true);
        PHASE1(tt, bf0, af1, bf1, true, true, true);
        PHASE0(tt + 1, af1, bf1, true);
        PHASE1(tt + 1, bf1, af0, bf0, true, true, true);
    }
    // t = NT-2 (even -> consumes set 0): no staging left; drain vmem once.
    PHASE0(NT - 2, af0, bf0, false);
    PHASE1(NT - 2, bf0, af1, bf1, false, true, false);
    // t = NT-1 (consumes set 1): last tile, no reads/stage/barrier needed.
    PHASE0(NT - 1, af1, bf1, false);
    PHASE1(NT - 1, bf1, af0, bf0, false, false, false);

#undef PHASE0
#undef PHASE1
#undef STAGE_A
#undef STAGE_B

    // epilogue: C/D layout col=lane&15, row=quad*4+reg (dtype-independent)
    float bv[4];
#pragma unroll
    for (int nj = 0; nj < 4; ++nj)
        bv[nj] = bias[n_block + wn + nj * 16 + l15];

#pragma unroll
    for (int mi = 0; mi < 8; ++mi) {
        const size_t row0 = m_block + wm + mi * 16 + quad * 4;
        const f4v sv = *(const f4v*)&s[row0];
#pragma unroll
        for (int nj = 0; nj < 4; ++nj) {
            const size_t col = n_block + wn + nj * 16 + l15;
            __builtin_nontemporal_store((float)acc[mi][nj][0] * sv.x + bv[nj], &C[(row0 + 0) * N + col]);
            __builtin_nontemporal_store((float)acc[mi][nj][1] * sv.y + bv[nj], &C[(row0 + 1) * N + col]);
            __builtin_nontemporal_store((float)acc[mi][nj][2] * sv.z + bv[nj], &C[(row0 + 2) * N + col]);
            __builtin_nontemporal_store((float)acc[mi][nj][3] * sv.w + bv[nj], &C[(row0 + 3) * N + col]);
        }
    }
}

extern "C" void kernel_launch(void* const* d_in, const int* in_sizes, int n_in,
                              void* d_out, int out_size, void* d_ws, size_t ws_size,
                              hipStream_t stream) {
    const float* x  = (const float*)d_in[0];   // [M,K]
    const float* w  = (const float*)d_in[1];   // [N,K]
    const float* bs = (const float*)d_in[2];   // [N]
    float* out = (float*)d_out;                // [M,N]

    const int N = in_sizes[2];
    const int K = in_sizes[1] / N;
    const int M = in_sizes[0] / K;

    i8*    xq = (i8*)d_ws;                          // [M,K] int8
    i8*    wq = xq + (size_t)M * K;                 // [N,K] int8 (+-1)
    float* s  = (float*)(wq + (size_t)N * K);       // [M] fp32 row scales

    const int xblocks = M;
    const int wblocks = (int)(((size_t)N * K) / (256 * 16));
    quant_fused<<<xblocks + wblocks, 256, 0, stream>>>(
        (const f4v*)x, (const f4v*)w, xq, wq, s, K, xblocks);

    // 96 KB dynamic LDS needs the opt-in (static limit is 64 KB).
    static bool lds_opt_in = false;
    if (!lds_opt_in) {
        hipFuncSetAttribute((const void*)gemm_i8_bt,
                            hipFuncAttributeMaxDynamicSharedMemorySize,
                            NBUF * BUFSZ);
        lds_opt_in = true;
    }
    const int nblocks = (M / BM) * (N / BN);   // 512
    gemm_i8_bt<<<nblocks, 512, NBUF * BUFSZ, stream>>>(xq, wq, s, bs, out, M, N, K);
}